// Round 1
// baseline (1028.021 us; speedup 1.0000x reference)
//
#include <hip/hip_runtime.h>
#include <hip/hip_bf16.h>
#include <stdint.h>

#define NN 50000
#define NE 600000
#define NP 200000

// ---------------- graph build ----------------

__global__ void count_kernel(const int* __restrict__ rows, int* __restrict__ counts) {
  int e = blockIdx.x * 256 + threadIdx.x;
  if (e < NE) atomicAdd(&counts[rows[e]], 1);
}

__global__ void dis_kernel(const int* __restrict__ counts, float* __restrict__ dis) {
  int i = blockIdx.x * 256 + threadIdx.x;
  if (i < NN) dis[i] = rsqrtf((float)counts[i] + 1.0f);  // +1 = self loop; deg>0 always
}

__global__ __launch_bounds__(1024) void scan_kernel(const int* __restrict__ counts,
                                                    int* __restrict__ row_ptr,
                                                    int* __restrict__ cursor) {
  __shared__ int partial[1024];
  const int t = threadIdx.x;
  const int CH = (NN + 1023) / 1024;  // 49
  int lo = t * CH; if (lo > NN) lo = NN;
  int hi = lo + CH; if (hi > NN) hi = NN;
  int s = 0;
  for (int i = lo; i < hi; ++i) s += counts[i];
  partial[t] = s;
  __syncthreads();
  for (int off = 1; off < 1024; off <<= 1) {
    int add = (t >= off) ? partial[t - off] : 0;
    __syncthreads();
    partial[t] += add;
    __syncthreads();
  }
  int run = partial[t] - s;  // exclusive base
  for (int i = lo; i < hi; ++i) {
    row_ptr[i] = run;
    cursor[i] = run;
    run += counts[i];
  }
  if (t == 1023) row_ptr[NN] = NE;
}

__global__ void fill_kernel(const int* __restrict__ rows, const int* __restrict__ cols,
                            int* __restrict__ cursor, int* __restrict__ csr_col) {
  int e = blockIdx.x * 256 + threadIdx.x;
  if (e < NE) {
    int r = rows[e];
    int pos = atomicAdd(&cursor[r], 1);
    csr_col[pos] = cols[e];
  }
}

// ---------------- GEMM: out[M x 128] = A[M x K] @ W[K x 128], epilogue ----------------
// MODE 0: out += bias (aux = bias[128])      (embedding)
// MODE 1: out *= dis[row] (aux = dis[M])     (conv h' = (x@W) * dis_row)

template<int K, int MODE>
__global__ __launch_bounds__(256) void gemm_kernel(const float* __restrict__ A,
                                                   const float* __restrict__ W,
                                                   const float* __restrict__ aux,
                                                   float* __restrict__ out, int M) {
  __shared__ float Al[64][36];
  __shared__ float Wl[32][132];
  const int tid = threadIdx.x;
  const int bm = blockIdx.x * 64;
  const int tc = tid & 31;   // col group: c0 = tc*4
  const int tr = tid >> 5;   // row group: r0 = tr*8
  const int sp = tid >> 2, sq = tid & 3;  // staging: pair (row, quarter)
  float acc[8][4] = {};

  for (int kb = 0; kb < K; kb += 32) {
    // stage A tile 64x32
    int arow = bm + sp;
    float4 v0 = make_float4(0.f, 0.f, 0.f, 0.f), v1 = v0;
    if (arow < M) {
      const float* src = A + (size_t)arow * K + kb;
      v0 = *(const float4*)(src + sq * 8);
      v1 = *(const float4*)(src + sq * 8 + 4);
    }
    *(float4*)&Al[sp][sq * 8]     = v0;
    *(float4*)&Al[sp][sq * 8 + 4] = v1;
    // stage W chunk 32x128
    const float* wsrc = W + (size_t)kb * 128;
#pragma unroll
    for (int i = 0; i < 4; ++i) {
      int f4 = tid + 256 * i;
      int k = f4 >> 5, c4 = f4 & 31;
      *(float4*)&Wl[k][c4 * 4] = *(const float4*)(wsrc + k * 128 + c4 * 4);
    }
    __syncthreads();
#pragma unroll
    for (int kk4 = 0; kk4 < 8; ++kk4) {
      float4 a4[8], w4[4];
#pragma unroll
      for (int r = 0; r < 8; ++r) a4[r] = *(const float4*)&Al[tr * 8 + r][kk4 * 4];
#pragma unroll
      for (int j = 0; j < 4; ++j) w4[j] = *(const float4*)&Wl[kk4 * 4 + j][tc * 4];
#pragma unroll
      for (int r = 0; r < 8; ++r) {
        acc[r][0] += a4[r].x * w4[0].x + a4[r].y * w4[1].x + a4[r].z * w4[2].x + a4[r].w * w4[3].x;
        acc[r][1] += a4[r].x * w4[0].y + a4[r].y * w4[1].y + a4[r].z * w4[2].y + a4[r].w * w4[3].y;
        acc[r][2] += a4[r].x * w4[0].z + a4[r].y * w4[1].z + a4[r].z * w4[2].z + a4[r].w * w4[3].z;
        acc[r][3] += a4[r].x * w4[0].w + a4[r].y * w4[1].w + a4[r].z * w4[2].w + a4[r].w * w4[3].w;
      }
    }
    __syncthreads();
  }
  float4 bv = make_float4(0.f, 0.f, 0.f, 0.f);
  if constexpr (MODE == 0) bv = *(const float4*)(aux + tc * 4);
#pragma unroll
  for (int r = 0; r < 8; ++r) {
    int row = bm + tr * 8 + r;
    if (row < M) {
      float4 v;
      if constexpr (MODE == 0) {
        v.x = acc[r][0] + bv.x; v.y = acc[r][1] + bv.y;
        v.z = acc[r][2] + bv.z; v.w = acc[r][3] + bv.w;
      } else {
        float dv = aux[row];
        v.x = acc[r][0] * dv; v.y = acc[r][1] * dv;
        v.z = acc[r][2] * dv; v.w = acc[r][3] * dv;
      }
      *(float4*)(out + (size_t)row * 128 + tc * 4) = v;
    }
  }
}

// ---------------- aggregation + bias + BN + ReLU ----------------
// x[i] = relu(BN(dis[i] * (h'[i] + sum_{c in N(i)} h'[c]) + b))

__global__ __launch_bounds__(128) void agg_kernel(const float* __restrict__ hp,
    const int* __restrict__ row_ptr, const int* __restrict__ csr_col,
    const float* __restrict__ dis, const float* __restrict__ cb,
    const float* __restrict__ gamma, const float* __restrict__ beta,
    const float* __restrict__ mean, const float* __restrict__ var,
    float* __restrict__ xout) {
  const int i = blockIdx.x;
  const int c = threadIdx.x;
  float acc = hp[(size_t)i * 128 + c];  // self loop
  const int s = row_ptr[i], e = row_ptr[i + 1];
  for (int j = s; j < e; ++j) {
    acc += hp[(size_t)csr_col[j] * 128 + c];
  }
  float v = dis[i] * acc + cb[c];
  v = (v - mean[c]) * rsqrtf(var[c] + 1e-5f) * gamma[c] + beta[c];
  xout[(size_t)i * 128 + c] = fmaxf(v, 0.f);
}

// ---------------- fused pair MLP ----------------
// per pair: z = [x[i0](128) | x[i1](128) | pf(32)]; h1=relu(z@W1+b1); h2=relu(h1@W2+b2); out=h2.W3+b3

__global__ __launch_bounds__(256) void mlp_kernel(
    const float* __restrict__ x, const int* __restrict__ pairs, const float* __restrict__ pf,
    const float* __restrict__ W1, const float* __restrict__ b1,
    const float* __restrict__ W2, const float* __restrict__ b2,
    const float* __restrict__ W3, const float* __restrict__ b3,
    float* __restrict__ out) {
  __shared__ float H1l[64 * 132];
  __shared__ float SA[6528];
  float* Zl  = SA;          // [64][36]   (phase 1)
  float* W1l = SA + 2304;   // [32][132]  (phase 1)
  float* W2l = SA;          // [32][68]   (phase 2)
  float* H2l = SA + 2176;   // [64][68]   (phase 2/3)

  const int tid = threadIdx.x;
  const int pb = blockIdx.x * 64;

  const int sp = tid >> 2, sq = tid & 3;  // staging: pair, quarter
  const int gp = pb + sp;
  const int i0 = pairs[2 * gp];
  const int i1 = pairs[2 * gp + 1];

  const int tc = tid & 31;   // c0 = tc*4
  const int tr = tid >> 5;   // r0 = tr*8
  float acc[8][4] = {};

  // ---- phase 1: H1 = relu(Z @ W1 + b1), Z gathered on the fly, K=288 in 9 chunks
  for (int kb = 0; kb < 9; ++kb) {
    const float* src;
    if (kb < 4)      src = x + (size_t)i0 * 128 + kb * 32;
    else if (kb < 8) src = x + (size_t)i1 * 128 + (kb - 4) * 32;
    else             src = pf + (size_t)gp * 32;
    float4 v0 = *(const float4*)(src + sq * 8);
    float4 v1 = *(const float4*)(src + sq * 8 + 4);
    *(float4*)&Zl[sp * 36 + sq * 8]     = v0;
    *(float4*)&Zl[sp * 36 + sq * 8 + 4] = v1;
    const float* wsrc = W1 + (size_t)kb * 32 * 128;
#pragma unroll
    for (int i = 0; i < 4; ++i) {
      int f4 = tid + 256 * i;
      int k = f4 >> 5, c4 = f4 & 31;
      *(float4*)&W1l[k * 132 + c4 * 4] = *(const float4*)(wsrc + k * 128 + c4 * 4);
    }
    __syncthreads();
#pragma unroll
    for (int kk4 = 0; kk4 < 8; ++kk4) {
      float4 a4[8], w4[4];
#pragma unroll
      for (int r = 0; r < 8; ++r) a4[r] = *(const float4*)&Zl[(tr * 8 + r) * 36 + kk4 * 4];
#pragma unroll
      for (int j = 0; j < 4; ++j) w4[j] = *(const float4*)&W1l[(kk4 * 4 + j) * 132 + tc * 4];
#pragma unroll
      for (int r = 0; r < 8; ++r) {
        acc[r][0] += a4[r].x * w4[0].x + a4[r].y * w4[1].x + a4[r].z * w4[2].x + a4[r].w * w4[3].x;
        acc[r][1] += a4[r].x * w4[0].y + a4[r].y * w4[1].y + a4[r].z * w4[2].y + a4[r].w * w4[3].y;
        acc[r][2] += a4[r].x * w4[0].z + a4[r].y * w4[1].z + a4[r].z * w4[2].z + a4[r].w * w4[3].z;
        acc[r][3] += a4[r].x * w4[0].w + a4[r].y * w4[1].w + a4[r].z * w4[2].w + a4[r].w * w4[3].w;
      }
    }
    __syncthreads();
  }
  {
    float4 bv = *(const float4*)(b1 + tc * 4);
#pragma unroll
    for (int r = 0; r < 8; ++r) {
      float4 hv;
      hv.x = fmaxf(acc[r][0] + bv.x, 0.f);
      hv.y = fmaxf(acc[r][1] + bv.y, 0.f);
      hv.z = fmaxf(acc[r][2] + bv.z, 0.f);
      hv.w = fmaxf(acc[r][3] + bv.w, 0.f);
      *(float4*)&H1l[(tr * 8 + r) * 132 + tc * 4] = hv;
    }
  }
  __syncthreads();

  // ---- phase 2: H2 = relu(H1 @ W2 + b2), 64x64, K=128 in 4 chunks
  const int tc2 = tid & 15;  // c0 = tc2*4
  const int tr2 = tid >> 4;  // r0 = tr2*4
  float acc2[4][4] = {};
  for (int kb = 0; kb < 4; ++kb) {
    const float* wsrc = W2 + (size_t)kb * 32 * 64;
#pragma unroll
    for (int i = 0; i < 2; ++i) {
      int f4 = tid + 256 * i;
      int k = f4 >> 4, c4 = f4 & 15;
      *(float4*)&W2l[k * 68 + c4 * 4] = *(const float4*)(wsrc + k * 64 + c4 * 4);
    }
    __syncthreads();
#pragma unroll
    for (int kk4 = 0; kk4 < 8; ++kk4) {
      float4 a4[4], w4[4];
#pragma unroll
      for (int r = 0; r < 4; ++r) a4[r] = *(const float4*)&H1l[(tr2 * 4 + r) * 132 + kb * 32 + kk4 * 4];
#pragma unroll
      for (int j = 0; j < 4; ++j) w4[j] = *(const float4*)&W2l[(kk4 * 4 + j) * 68 + tc2 * 4];
#pragma unroll
      for (int r = 0; r < 4; ++r) {
        acc2[r][0] += a4[r].x * w4[0].x + a4[r].y * w4[1].x + a4[r].z * w4[2].x + a4[r].w * w4[3].x;
        acc2[r][1] += a4[r].x * w4[0].y + a4[r].y * w4[1].y + a4[r].z * w4[2].y + a4[r].w * w4[3].y;
        acc2[r][2] += a4[r].x * w4[0].z + a4[r].y * w4[1].z + a4[r].z * w4[2].z + a4[r].w * w4[3].z;
        acc2[r][3] += a4[r].x * w4[0].w + a4[r].y * w4[1].w + a4[r].z * w4[2].w + a4[r].w * w4[3].w;
      }
    }
    __syncthreads();
  }
  {
    float4 bv = *(const float4*)(b2 + tc2 * 4);
#pragma unroll
    for (int r = 0; r < 4; ++r) {
      float4 hv;
      hv.x = fmaxf(acc2[r][0] + bv.x, 0.f);
      hv.y = fmaxf(acc2[r][1] + bv.y, 0.f);
      hv.z = fmaxf(acc2[r][2] + bv.z, 0.f);
      hv.w = fmaxf(acc2[r][3] + bv.w, 0.f);
      *(float4*)&H2l[(tr2 * 4 + r) * 68 + tc2 * 4] = hv;
    }
  }
  __syncthreads();

  // ---- phase 3: out = H2 . W3 + b3
  const int p3 = tid >> 2, q3 = tid & 3;
  float s = 0.f;
#pragma unroll
  for (int i = 0; i < 16; ++i) {
    int c = q3 * 16 + i;
    s += H2l[p3 * 68 + c] * W3[c];
  }
  s += __shfl_xor(s, 1);
  s += __shfl_xor(s, 2);
  if (q3 == 0) out[pb + p3] = s + b3[0];
}

// ---------------- launch ----------------

extern "C" void kernel_launch(void* const* d_in, const int* in_sizes, int n_in,
                              void* d_out, int out_size, void* d_ws, size_t ws_size,
                              hipStream_t stream) {
  (void)in_sizes; (void)n_in; (void)out_size; (void)ws_size;
  const float* atom  = (const float*)d_in[0];
  const int*   eidx  = (const int*)d_in[1];
  const int*   pairs = (const int*)d_in[2];
  const float* pfeat = (const float*)d_in[3];
  const float* embW  = (const float*)d_in[4];
  const float* embB  = (const float*)d_in[5];
  const float* convW = (const float*)d_in[6];
  const float* convB = (const float*)d_in[7];
  const float* bng   = (const float*)d_in[8];
  const float* bnb   = (const float*)d_in[9];
  const float* bnm   = (const float*)d_in[10];
  const float* bnv   = (const float*)d_in[11];
  const float* W1    = (const float*)d_in[12];
  const float* b1    = (const float*)d_in[13];
  const float* W2    = (const float*)d_in[14];
  const float* b2    = (const float*)d_in[15];
  const float* W3    = (const float*)d_in[16];
  const float* b3    = (const float*)d_in[17];
  float* out = (float*)d_out;

  uintptr_t base = (uintptr_t)d_ws;
  auto alloc = [&](size_t bytes) -> uintptr_t {
    uintptr_t p = base;
    base += (bytes + 255) & ~(size_t)255;
    return p;
  };
  int*   counts   = (int*)alloc((size_t)NN * 4);
  int*   row_ptr  = (int*)alloc((size_t)(NN + 1) * 4);
  int*   cursor   = (int*)alloc((size_t)NN * 4);
  int*   csr_col  = (int*)alloc((size_t)NE * 4);
  float* dis      = (float*)alloc((size_t)NN * 4);
  float* x        = (float*)alloc((size_t)NN * 128 * 4);
  float* h        = (float*)alloc((size_t)NN * 128 * 4);

  const int* erow = eidx;
  const int* ecol = eidx + NE;

  hipMemsetAsync(counts, 0, (size_t)NN * 4, stream);
  count_kernel<<<(NE + 255) / 256, 256, 0, stream>>>(erow, counts);
  dis_kernel<<<(NN + 255) / 256, 256, 0, stream>>>(counts, dis);
  scan_kernel<<<1, 1024, 0, stream>>>(counts, row_ptr, cursor);
  fill_kernel<<<(NE + 255) / 256, 256, 0, stream>>>(erow, ecol, cursor, csr_col);

  // x = atom @ embW + embB
  gemm_kernel<64, 0><<<(NN + 63) / 64, 256, 0, stream>>>(atom, embW, embB, x, NN);

  for (int l = 0; l < 3; ++l) {
    // h' = (x @ convW[l]) * dis_row
    gemm_kernel<128, 1><<<(NN + 63) / 64, 256, 0, stream>>>(x, convW + (size_t)l * 128 * 128, dis, h, NN);
    // x = relu(BN(dis_i * (sum) + b))
    agg_kernel<<<NN, 128, 0, stream>>>(h, row_ptr, csr_col, dis,
                                       convB + (size_t)l * 128,
                                       bng + (size_t)l * 128, bnb + (size_t)l * 128,
                                       bnm + (size_t)l * 128, bnv + (size_t)l * 128, x);
  }

  mlp_kernel<<<NP / 64, 256, 0, stream>>>(x, pairs, pfeat, W1, b1, W2, b2, W3, b3, out);
}

// Round 2
// 669.436 us; speedup vs baseline: 1.5357x; 1.5357x over previous
//
#include <hip/hip_runtime.h>
#include <hip/hip_bf16.h>
#include <stdint.h>

#define NN 50000
#define NE 600000
#define NP 200000

typedef __attribute__((ext_vector_type(8))) short short8;
typedef __attribute__((ext_vector_type(4))) float f32x4;

static __device__ __forceinline__ unsigned short f2bf(float f) {
  union { float f; unsigned u; } a; a.f = f;
  unsigned r = a.u + 0x7fff + ((a.u >> 16) & 1);
  return (unsigned short)(r >> 16);
}

// ---------------- graph build ----------------

__global__ void count_kernel(const int* __restrict__ rows, int* __restrict__ counts) {
  int e = blockIdx.x * 256 + threadIdx.x;
  if (e < NE) atomicAdd(&counts[rows[e]], 1);
}

__global__ void dis_kernel(const int* __restrict__ counts, float* __restrict__ dis) {
  int i = blockIdx.x * 256 + threadIdx.x;
  if (i < NN) dis[i] = rsqrtf((float)counts[i] + 1.0f);
}

__global__ __launch_bounds__(1024) void scan_kernel(const int* __restrict__ counts,
                                                    int* __restrict__ row_ptr,
                                                    int* __restrict__ cursor) {
  __shared__ int partial[1024];
  const int t = threadIdx.x;
  const int CH = (NN + 1023) / 1024;
  int lo = t * CH; if (lo > NN) lo = NN;
  int hi = lo + CH; if (hi > NN) hi = NN;
  int s = 0;
  for (int i = lo; i < hi; ++i) s += counts[i];
  partial[t] = s;
  __syncthreads();
  for (int off = 1; off < 1024; off <<= 1) {
    int add = (t >= off) ? partial[t - off] : 0;
    __syncthreads();
    partial[t] += add;
    __syncthreads();
  }
  int run = partial[t] - s;
  for (int i = lo; i < hi; ++i) {
    row_ptr[i] = run;
    cursor[i] = run;
    run += counts[i];
  }
  if (t == 1023) row_ptr[NN] = NE;
}

__global__ void fill_kernel(const int* __restrict__ rows, const int* __restrict__ cols,
                            int* __restrict__ cursor, int* __restrict__ csr_col) {
  int e = blockIdx.x * 256 + threadIdx.x;
  if (e < NE) {
    int r = rows[e];
    int pos = atomicAdd(&cursor[r], 1);
    csr_col[pos] = cols[e];
  }
}

// ---------------- fp32 GEMM (embed + convs) ----------------

template<int K, int MODE>
__global__ __launch_bounds__(256) void gemm_kernel(const float* __restrict__ A,
                                                   const float* __restrict__ W,
                                                   const float* __restrict__ aux,
                                                   float* __restrict__ out, int M) {
  __shared__ float Al[64][36];
  __shared__ float Wl[32][132];
  const int tid = threadIdx.x;
  const int bm = blockIdx.x * 64;
  const int tc = tid & 31;
  const int tr = tid >> 5;
  const int sp = tid >> 2, sq = tid & 3;
  float acc[8][4] = {};

  for (int kb = 0; kb < K; kb += 32) {
    int arow = bm + sp;
    float4 v0 = make_float4(0.f, 0.f, 0.f, 0.f), v1 = v0;
    if (arow < M) {
      const float* src = A + (size_t)arow * K + kb;
      v0 = *(const float4*)(src + sq * 8);
      v1 = *(const float4*)(src + sq * 8 + 4);
    }
    *(float4*)&Al[sp][sq * 8]     = v0;
    *(float4*)&Al[sp][sq * 8 + 4] = v1;
    const float* wsrc = W + (size_t)kb * 128;
#pragma unroll
    for (int i = 0; i < 4; ++i) {
      int f4 = tid + 256 * i;
      int k = f4 >> 5, c4 = f4 & 31;
      *(float4*)&Wl[k][c4 * 4] = *(const float4*)(wsrc + k * 128 + c4 * 4);
    }
    __syncthreads();
#pragma unroll
    for (int kk4 = 0; kk4 < 8; ++kk4) {
      float4 a4[8], w4[4];
#pragma unroll
      for (int r = 0; r < 8; ++r) a4[r] = *(const float4*)&Al[tr * 8 + r][kk4 * 4];
#pragma unroll
      for (int j = 0; j < 4; ++j) w4[j] = *(const float4*)&Wl[kk4 * 4 + j][tc * 4];
#pragma unroll
      for (int r = 0; r < 8; ++r) {
        acc[r][0] += a4[r].x * w4[0].x + a4[r].y * w4[1].x + a4[r].z * w4[2].x + a4[r].w * w4[3].x;
        acc[r][1] += a4[r].x * w4[0].y + a4[r].y * w4[1].y + a4[r].z * w4[2].y + a4[r].w * w4[3].y;
        acc[r][2] += a4[r].x * w4[0].z + a4[r].y * w4[1].z + a4[r].z * w4[2].z + a4[r].w * w4[3].z;
        acc[r][3] += a4[r].x * w4[0].w + a4[r].y * w4[1].w + a4[r].z * w4[2].w + a4[r].w * w4[3].w;
      }
    }
    __syncthreads();
  }
  float4 bv = make_float4(0.f, 0.f, 0.f, 0.f);
  if constexpr (MODE == 0) bv = *(const float4*)(aux + tc * 4);
#pragma unroll
  for (int r = 0; r < 8; ++r) {
    int row = bm + tr * 8 + r;
    if (row < M) {
      float4 v;
      if constexpr (MODE == 0) {
        v.x = acc[r][0] + bv.x; v.y = acc[r][1] + bv.y;
        v.z = acc[r][2] + bv.z; v.w = acc[r][3] + bv.w;
      } else {
        float dv = aux[row];
        v.x = acc[r][0] * dv; v.y = acc[r][1] * dv;
        v.z = acc[r][2] * dv; v.w = acc[r][3] * dv;
      }
      *(float4*)(out + (size_t)row * 128 + tc * 4) = v;
    }
  }
}

// ---------------- aggregation + bias + BN + ReLU ----------------

__global__ __launch_bounds__(128) void agg_kernel(const float* __restrict__ hp,
    const int* __restrict__ row_ptr, const int* __restrict__ csr_col,
    const float* __restrict__ dis, const float* __restrict__ cb,
    const float* __restrict__ gamma, const float* __restrict__ beta,
    const float* __restrict__ mean, const float* __restrict__ var,
    float* __restrict__ xout) {
  const int i = blockIdx.x;
  const int c = threadIdx.x;
  float acc = hp[(size_t)i * 128 + c];
  const int s = row_ptr[i], e = row_ptr[i + 1];
  for (int j = s; j < e; ++j) {
    acc += hp[(size_t)csr_col[j] * 128 + c];
  }
  float v = dis[i] * acc + cb[c];
  v = (v - mean[c]) * rsqrtf(var[c] + 1e-5f) * gamma[c] + beta[c];
  xout[(size_t)i * 128 + c] = fmaxf(v, 0.f);
}

// ---------------- bf16 prep kernels ----------------

// x (NN*128 f32) -> x_bf (bf16)
__global__ void cast_x_kernel(const float* __restrict__ x, unsigned short* __restrict__ xb) {
  int i = blockIdx.x * 256 + threadIdx.x;           // group of 8
  const int NG = NN * 128 / 8;
  if (i >= NG) return;
  const float4* s = (const float4*)(x + (size_t)i * 8);
  float4 v0 = s[0], v1 = s[1];
  short8 o;
  o[0] = (short)f2bf(v0.x); o[1] = (short)f2bf(v0.y);
  o[2] = (short)f2bf(v0.z); o[3] = (short)f2bf(v0.w);
  o[4] = (short)f2bf(v1.x); o[5] = (short)f2bf(v1.y);
  o[6] = (short)f2bf(v1.z); o[7] = (short)f2bf(v1.w);
  *(short8*)(xb + (size_t)i * 8) = o;
}

// W1 (288x128) -> W1T (128x288) bf16 ; W2 (128x64) -> W2T (64x128) bf16
__global__ void transpose_w_kernel(const float* __restrict__ W1, const float* __restrict__ W2,
                                   unsigned short* __restrict__ W1T, unsigned short* __restrict__ W2T) {
  int idx = blockIdx.x * 256 + threadIdx.x;
  if (idx < 288 * 128) {
    int n = idx / 288, k = idx % 288;
    W1T[idx] = f2bf(W1[(size_t)k * 128 + n]);
  } else if (idx < 288 * 128 + 128 * 64) {
    int i2 = idx - 288 * 128;
    int n = i2 / 128, k = i2 % 128;
    W2T[i2] = f2bf(W2[(size_t)k * 64 + n]);
  }
}

// ---------------- MFMA pair MLP ----------------
// block: 128 pairs x 128 cols, 4 waves, wave = 32 pairs.
// A layout: lane holds row=(lane&15), k=(lane>>4)*8+e  (8 contiguous bf16)
// B layout: lane holds col=(lane&15), k=(lane>>4)*8+e  (row of W^T)
// C layout: col=lane&15, row=(lane>>4)*4+reg

__global__ __launch_bounds__(256, 4) void mlp2_kernel(
    const unsigned short* __restrict__ xb, const int* __restrict__ pairs,
    const float* __restrict__ pf,
    const unsigned short* __restrict__ W1T, const float* __restrict__ b1,
    const unsigned short* __restrict__ W2T, const float* __restrict__ b2,
    const float* __restrict__ W3, const float* __restrict__ b3,
    float* __restrict__ out) {
  __shared__ unsigned short H1[128 * 136];   // padded stride 136

  const int tid  = threadIdx.x;
  const int lane = tid & 63;
  const int w    = tid >> 6;
  const int pb   = blockIdx.x * 128;
  const int rowbase = w * 32;
  const int l15  = lane & 15;
  const int khi  = (lane >> 4) * 8;   // k sub-offset 0/8/16/24

  // pair indices for the two 16-row sub-tiles this wave owns
  int gp0 = pb + rowbase + l15;       if (gp0 >= NP) gp0 = NP - 1;
  int gp1 = pb + rowbase + 16 + l15;  if (gp1 >= NP) gp1 = NP - 1;
  const int2 pr0 = ((const int2*)pairs)[gp0];
  const int2 pr1 = ((const int2*)pairs)[gp1];

  f32x4 acc[2][8];
#pragma unroll
  for (int p = 0; p < 2; ++p)
#pragma unroll
    for (int c = 0; c < 8; ++c) acc[p][c] = (f32x4){0.f, 0.f, 0.f, 0.f};

  // ---- phase 1: H1 = relu(Z @ W1 + b1), K = 288 ----
#pragma unroll
  for (int kb = 0; kb < 9; ++kb) {
    short8 a0, a1;
    if (kb < 8) {
      int r0 = (kb < 4) ? pr0.x : pr0.y;
      int r1 = (kb < 4) ? pr1.x : pr1.y;
      int ko = (kb & 3) * 32 + khi;
      a0 = *(const short8*)(xb + (size_t)r0 * 128 + ko);
      a1 = *(const short8*)(xb + (size_t)r1 * 128 + ko);
    } else {
      const float* q0 = pf + (size_t)gp0 * 32 + khi;
      const float* q1 = pf + (size_t)gp1 * 32 + khi;
#pragma unroll
      for (int j = 0; j < 8; ++j) { a0[j] = (short)f2bf(q0[j]); a1[j] = (short)f2bf(q1[j]); }
    }
    const unsigned short* wrow = W1T + (size_t)kb * 32 + khi;
#pragma unroll
    for (int ct = 0; ct < 8; ++ct) {
      short8 bfrag = *(const short8*)(wrow + (size_t)(ct * 16 + l15) * 288);
      acc[0][ct] = __builtin_amdgcn_mfma_f32_16x16x32_bf16(a0, bfrag, acc[0][ct], 0, 0, 0);
      acc[1][ct] = __builtin_amdgcn_mfma_f32_16x16x32_bf16(a1, bfrag, acc[1][ct], 0, 0, 0);
    }
  }

  // epilogue: bias + relu -> bf16 -> LDS
#pragma unroll
  for (int ct = 0; ct < 8; ++ct) {
    float bv = b1[ct * 16 + l15];
    int col = ct * 16 + l15;
#pragma unroll
    for (int p = 0; p < 2; ++p) {
#pragma unroll
      for (int r = 0; r < 4; ++r) {
        int row = rowbase + p * 16 + (lane >> 4) * 4 + r;
        float v = fmaxf(acc[p][ct][r] + bv, 0.f);
        H1[row * 136 + col] = f2bf(v);
      }
    }
  }
  __syncthreads();

  // ---- phase 2: H2 = relu(H1 @ W2 + b2), 32 rows x 64 cols per wave, K=128 ----
  f32x4 acc2[2][4];
#pragma unroll
  for (int p = 0; p < 2; ++p)
#pragma unroll
    for (int c = 0; c < 4; ++c) acc2[p][c] = (f32x4){0.f, 0.f, 0.f, 0.f};

#pragma unroll
  for (int kb = 0; kb < 4; ++kb) {
    int ko = kb * 32 + khi;
    short8 a0 = *(const short8*)&H1[(rowbase + l15) * 136 + ko];
    short8 a1 = *(const short8*)&H1[(rowbase + 16 + l15) * 136 + ko];
    const unsigned short* wrow = W2T + (size_t)ko;
#pragma unroll
    for (int ct = 0; ct < 4; ++ct) {
      short8 bfrag = *(const short8*)(wrow + (size_t)(ct * 16 + l15) * 128);
      acc2[0][ct] = __builtin_amdgcn_mfma_f32_16x16x32_bf16(a0, bfrag, acc2[0][ct], 0, 0, 0);
      acc2[1][ct] = __builtin_amdgcn_mfma_f32_16x16x32_bf16(a1, bfrag, acc2[1][ct], 0, 0, 0);
    }
  }

  // ---- phase 3: out = relu(H2 + b2) . W3 + b3, in registers ----
  float w3v[4], b2v[4];
#pragma unroll
  for (int ct = 0; ct < 4; ++ct) {
    w3v[ct] = W3[ct * 16 + l15];
    b2v[ct] = b2[ct * 16 + l15];
  }
  float b3v = b3[0];
#pragma unroll
  for (int p = 0; p < 2; ++p) {
#pragma unroll
    for (int r = 0; r < 4; ++r) {
      float s = 0.f;
#pragma unroll
      for (int ct = 0; ct < 4; ++ct) {
        float h2 = fmaxf(acc2[p][ct][r] + b2v[ct], 0.f);
        s += h2 * w3v[ct];
      }
      s += __shfl_xor(s, 1);
      s += __shfl_xor(s, 2);
      s += __shfl_xor(s, 4);
      s += __shfl_xor(s, 8);
      int row = pb + rowbase + p * 16 + (lane >> 4) * 4 + r;
      if (l15 == 0 && row < NP) out[row] = s + b3v;
    }
  }
}

// ---------------- launch ----------------

extern "C" void kernel_launch(void* const* d_in, const int* in_sizes, int n_in,
                              void* d_out, int out_size, void* d_ws, size_t ws_size,
                              hipStream_t stream) {
  (void)in_sizes; (void)n_in; (void)out_size; (void)ws_size;
  const float* atom  = (const float*)d_in[0];
  const int*   eidx  = (const int*)d_in[1];
  const int*   pairs = (const int*)d_in[2];
  const float* pfeat = (const float*)d_in[3];
  const float* embW  = (const float*)d_in[4];
  const float* embB  = (const float*)d_in[5];
  const float* convW = (const float*)d_in[6];
  const float* convB = (const float*)d_in[7];
  const float* bng   = (const float*)d_in[8];
  const float* bnb   = (const float*)d_in[9];
  const float* bnm   = (const float*)d_in[10];
  const float* bnv   = (const float*)d_in[11];
  const float* W1    = (const float*)d_in[12];
  const float* b1    = (const float*)d_in[13];
  const float* W2    = (const float*)d_in[14];
  const float* b2    = (const float*)d_in[15];
  const float* W3    = (const float*)d_in[16];
  const float* b3    = (const float*)d_in[17];
  float* out = (float*)d_out;

  uintptr_t base = (uintptr_t)d_ws;
  auto alloc = [&](size_t bytes) -> uintptr_t {
    uintptr_t p = base;
    base += (bytes + 255) & ~(size_t)255;
    return p;
  };
  int*   counts   = (int*)alloc((size_t)NN * 4);
  int*   row_ptr  = (int*)alloc((size_t)(NN + 1) * 4);
  int*   cursor   = (int*)alloc((size_t)NN * 4);
  int*   csr_col  = (int*)alloc((size_t)NE * 4);
  float* dis      = (float*)alloc((size_t)NN * 4);
  float* x        = (float*)alloc((size_t)NN * 128 * 4);
  float* h        = (float*)alloc((size_t)NN * 128 * 4);

  // bf16 buffers overlay h (dead after last agg): 12.8MB + 73.7KB + 16KB < 25.6MB
  unsigned short* x_bf = (unsigned short*)h;
  unsigned short* W1T  = (unsigned short*)((char*)h + 12800000);
  unsigned short* W2T  = (unsigned short*)((char*)h + 12800000 + 73728 + 256);

  const int* erow = eidx;
  const int* ecol = eidx + NE;

  hipMemsetAsync(counts, 0, (size_t)NN * 4, stream);
  count_kernel<<<(NE + 255) / 256, 256, 0, stream>>>(erow, counts);
  dis_kernel<<<(NN + 255) / 256, 256, 0, stream>>>(counts, dis);
  scan_kernel<<<1, 1024, 0, stream>>>(counts, row_ptr, cursor);
  fill_kernel<<<(NE + 255) / 256, 256, 0, stream>>>(erow, ecol, cursor, csr_col);

  gemm_kernel<64, 0><<<(NN + 63) / 64, 256, 0, stream>>>(atom, embW, embB, x, NN);

  for (int l = 0; l < 3; ++l) {
    gemm_kernel<128, 1><<<(NN + 63) / 64, 256, 0, stream>>>(x, convW + (size_t)l * 128 * 128, dis, h, NN);
    agg_kernel<<<NN, 128, 0, stream>>>(h, row_ptr, csr_col, dis,
                                       convB + (size_t)l * 128,
                                       bng + (size_t)l * 128, bnb + (size_t)l * 128,
                                       bnm + (size_t)l * 128, bnv + (size_t)l * 128, x);
  }

  // prep bf16 operands (h is dead now)
  transpose_w_kernel<<<(288 * 128 + 128 * 64 + 255) / 256, 256, 0, stream>>>(W1, W2, W1T, W2T);
  cast_x_kernel<<<(NN * 128 / 8 + 255) / 256, 256, 0, stream>>>(x, x_bf);

  mlp2_kernel<<<(NP + 127) / 128, 256, 0, stream>>>(x_bf, pairs, pfeat,
                                                    W1T, b1, W2T, b2, W3, b3, out);
}

// Round 3
// 501.239 us; speedup vs baseline: 2.0510x; 1.3356x over previous
//
#include <hip/hip_runtime.h>
#include <hip/hip_bf16.h>
#include <stdint.h>

#define NN 50000
#define NE 600000
#define NP 200000
#define SCAN_CHUNK 1024
#define NB_SCAN ((NN + SCAN_CHUNK - 1) / SCAN_CHUNK)   // 49

typedef __attribute__((ext_vector_type(8))) short short8;
typedef __attribute__((ext_vector_type(4))) float f32x4;

static __device__ __forceinline__ unsigned short f2bf(float f) {
  union { float f; unsigned u; } a; a.f = f;
  unsigned r = a.u + 0x7fff + ((a.u >> 16) & 1);
  return (unsigned short)(r >> 16);
}
static __device__ __forceinline__ float bf2f(unsigned short h) {
  union { unsigned u; float f; } a; a.u = ((unsigned)h) << 16;
  return a.f;
}

// ---------------- graph build ----------------

__global__ void count_kernel(const int* __restrict__ rows, int* __restrict__ counts) {
  int e = blockIdx.x * 256 + threadIdx.x;
  if (e < NE) atomicAdd(&counts[rows[e]], 1);
}

__global__ void dis_kernel(const int* __restrict__ counts, float* __restrict__ dis) {
  int i = blockIdx.x * 256 + threadIdx.x;
  if (i < NN) dis[i] = rsqrtf((float)counts[i] + 1.0f);
}

__global__ __launch_bounds__(256) void scan_partial(const int* __restrict__ counts,
                                                    int* __restrict__ bsum) {
  const int b = blockIdx.x, t = threadIdx.x;
  const int base = b * SCAN_CHUNK;
  int s = 0;
  for (int j = t; j < SCAN_CHUNK; j += 256) {
    int i = base + j;
    if (i < NN) s += counts[i];
  }
  __shared__ int red[4];
#pragma unroll
  for (int off = 32; off; off >>= 1) s += __shfl_down(s, off);
  if ((t & 63) == 0) red[t >> 6] = s;
  __syncthreads();
  if (t == 0) bsum[b] = red[0] + red[1] + red[2] + red[3];
}

__global__ void scan_mid(const int* __restrict__ bsum, int* __restrict__ bbase) {
  int t = threadIdx.x;  // 64 threads, one wave
  int v = (t < NB_SCAN) ? bsum[t] : 0;
  int orig = v;
#pragma unroll
  for (int off = 1; off < 64; off <<= 1) {
    int u = __shfl_up(v, off);
    if (t >= off) v += u;
  }
  if (t < NB_SCAN) bbase[t] = v - orig;
}

__global__ __launch_bounds__(256) void scan_final(const int* __restrict__ counts,
                                                  const int* __restrict__ bbase,
                                                  int* __restrict__ row_ptr,
                                                  int* __restrict__ cursor) {
  const int b = blockIdx.x, t = threadIdx.x;
  const int i0 = b * SCAN_CHUNK + t * 4;
  int c[4]; int s = 0;
#pragma unroll
  for (int r = 0; r < 4; ++r) { int i = i0 + r; c[r] = (i < NN) ? counts[i] : 0; s += c[r]; }
  __shared__ int sc[256];
  sc[t] = s;
  __syncthreads();
  for (int off = 1; off < 256; off <<= 1) {
    int add = (t >= off) ? sc[t - off] : 0;
    __syncthreads();
    sc[t] += add;
    __syncthreads();
  }
  int run = bbase[b] + sc[t] - s;
#pragma unroll
  for (int r = 0; r < 4; ++r) {
    int i = i0 + r;
    if (i < NN) { row_ptr[i] = run; cursor[i] = run; run += c[r]; }
  }
  if (b == 0 && t == 0) row_ptr[NN] = NE;
}

__global__ void fill_kernel(const int* __restrict__ rows, const int* __restrict__ cols,
                            int* __restrict__ cursor, int* __restrict__ csr_col) {
  int e = blockIdx.x * 256 + threadIdx.x;
  if (e < NE) {
    int r = rows[e];
    int pos = atomicAdd(&cursor[r], 1);
    csr_col[pos] = cols[e];
  }
}

// ---------------- weight prep: transpose + (split-)bf16 ----------------
// embT  [128][64]  hi/lo   from embW  [64][128]
// convT [3][128][128] hi/lo from convW[3][128][128]
// W1T   [128][288] bf16    from W1 [288][128]
// W2T   [64][128]  bf16    from W2 [128][64]

__global__ void prep_w(const float* __restrict__ embW, const float* __restrict__ convW,
                       const float* __restrict__ W1, const float* __restrict__ W2,
                       unsigned short* __restrict__ embT_hi, unsigned short* __restrict__ embT_lo,
                       unsigned short* __restrict__ convT_hi, unsigned short* __restrict__ convT_lo,
                       unsigned short* __restrict__ W1T, unsigned short* __restrict__ W2T) {
  int idx = blockIdx.x * 256 + threadIdx.x;
  if (idx < 8192) {
    int n = idx >> 6, k = idx & 63;
    float v = embW[(size_t)k * 128 + n];
    unsigned short h = f2bf(v);
    embT_hi[idx] = h;
    embT_lo[idx] = f2bf(v - bf2f(h));
  } else if (idx < 8192 + 49152) {
    int i2 = idx - 8192;
    int l = i2 >> 14, n = (i2 >> 7) & 127, k = i2 & 127;
    float v = convW[(size_t)l * 16384 + (size_t)k * 128 + n];
    unsigned short h = f2bf(v);
    convT_hi[i2] = h;
    convT_lo[i2] = f2bf(v - bf2f(h));
  } else if (idx < 8192 + 49152 + 36864) {
    int i3 = idx - 57344;
    int n = i3 / 288, k = i3 % 288;
    W1T[i3] = f2bf(W1[(size_t)k * 128 + n]);
  } else if (idx < 8192 + 49152 + 36864 + 8192) {
    int i4 = idx - 94208;
    int n = i4 >> 7, k = i4 & 127;
    W2T[i4] = f2bf(W2[(size_t)k * 64 + n]);
  }
}

// ---------------- aggregation: y[i] = dis[i] * (xs[i] + sum_{c in N(i)} xs[c]) ----------------

__global__ __launch_bounds__(128) void agg2_kernel(const float* __restrict__ xs,
    const int* __restrict__ row_ptr, const int* __restrict__ csr_col,
    const float* __restrict__ dis, float* __restrict__ y) {
  const int i = blockIdx.x;
  const int c = threadIdx.x;
  float acc = xs[(size_t)i * 128 + c];
  const int s = row_ptr[i], e = row_ptr[i + 1];
  for (int j = s; j < e; ++j) {
    acc += xs[(size_t)csr_col[j] * 128 + c];
  }
  y[(size_t)i * 128 + c] = dis[i] * acc;
}

// ---------------- split-bf16 MFMA GEMM: out = A[MxK] @ B[Kx128] (+epilogue) ----------------
// A fp32 split in-register to hi/lo bf16; B prepacked transposed hi/lo bf16.
// error ~2^-18 relative: effectively fp32.
// MODE 0 (embed): outf = dis[row] * (acc + bias)
// MODE 1 (conv, l<2): outf = dis[row] * relu(BN(acc + bias))
// MODE 2 (conv, l=2): outb = bf16(relu(BN(acc + bias)))

template<int K, int MODE>
__global__ __launch_bounds__(256) void mfma_gemm(
    const float* __restrict__ A,
    const unsigned short* __restrict__ BThi, const unsigned short* __restrict__ BTlo,
    const float* __restrict__ bias, const float* __restrict__ dis,
    const float* __restrict__ g, const float* __restrict__ be,
    const float* __restrict__ mn, const float* __restrict__ vr,
    float* __restrict__ outf, unsigned short* __restrict__ outb, int M) {
  const int tid  = threadIdx.x;
  const int lane = tid & 63;
  const int w    = tid >> 6;
  const int l15  = lane & 15;
  const int khi  = (lane >> 4) * 8;
  const int row  = blockIdx.x * 64 + w * 16 + l15;
  const int arow = (row < M) ? row : M - 1;

  f32x4 acc[8];
#pragma unroll
  for (int ct = 0; ct < 8; ++ct) acc[ct] = (f32x4){0.f, 0.f, 0.f, 0.f};

#pragma unroll
  for (int kb = 0; kb < K; kb += 32) {
    const float* asrc = A + (size_t)arow * K + kb + khi;
    float4 va0 = *(const float4*)(asrc);
    float4 va1 = *(const float4*)(asrc + 4);
    float av[8] = {va0.x, va0.y, va0.z, va0.w, va1.x, va1.y, va1.z, va1.w};
    short8 ahi, alo;
#pragma unroll
    for (int j = 0; j < 8; ++j) {
      unsigned short h = f2bf(av[j]);
      ahi[j] = (short)h;
      alo[j] = (short)f2bf(av[j] - bf2f(h));
    }
#pragma unroll
    for (int ct = 0; ct < 8; ++ct) {
      size_t woff = (size_t)(ct * 16 + l15) * K + kb + khi;
      short8 bhi = *(const short8*)(BThi + woff);
      short8 blo = *(const short8*)(BTlo + woff);
      acc[ct] = __builtin_amdgcn_mfma_f32_16x16x32_bf16(ahi, bhi, acc[ct], 0, 0, 0);
      acc[ct] = __builtin_amdgcn_mfma_f32_16x16x32_bf16(alo, bhi, acc[ct], 0, 0, 0);
      acc[ct] = __builtin_amdgcn_mfma_f32_16x16x32_bf16(ahi, blo, acc[ct], 0, 0, 0);
    }
  }

  const int orow0 = blockIdx.x * 64 + w * 16 + (lane >> 4) * 4;
  float dv[4];
  if constexpr (MODE != 2) {
#pragma unroll
    for (int r = 0; r < 4; ++r) dv[r] = (orow0 + r < M) ? dis[orow0 + r] : 0.f;
  }
#pragma unroll
  for (int ct = 0; ct < 8; ++ct) {
    int col = ct * 16 + l15;
    float bb = bias[col];
    float scale = 1.f, shift = 0.f;
    if constexpr (MODE >= 1) {
      float inv = rsqrtf(vr[col] + 1e-5f);
      scale = g[col] * inv;
      shift = be[col] - mn[col] * scale;
    }
#pragma unroll
    for (int r = 0; r < 4; ++r) {
      int orow = orow0 + r;
      if (orow < M) {
        float v = acc[ct][r] + bb;
        if constexpr (MODE >= 1) v = fmaxf(v * scale + shift, 0.f);
        if constexpr (MODE == 2) {
          outb[(size_t)orow * 128 + col] = f2bf(v);
        } else {
          outf[(size_t)orow * 128 + col] = v * dv[r];
        }
      }
    }
  }
}

// ---------------- MFMA pair MLP (unchanged from round 2) ----------------

__global__ __launch_bounds__(256, 4) void mlp2_kernel(
    const unsigned short* __restrict__ xb, const int* __restrict__ pairs,
    const float* __restrict__ pf,
    const unsigned short* __restrict__ W1T, const float* __restrict__ b1,
    const unsigned short* __restrict__ W2T, const float* __restrict__ b2,
    const float* __restrict__ W3, const float* __restrict__ b3,
    float* __restrict__ out) {
  __shared__ unsigned short H1[128 * 136];

  const int tid  = threadIdx.x;
  const int lane = tid & 63;
  const int w    = tid >> 6;
  const int pb   = blockIdx.x * 128;
  const int rowbase = w * 32;
  const int l15  = lane & 15;
  const int khi  = (lane >> 4) * 8;

  int gp0 = pb + rowbase + l15;       if (gp0 >= NP) gp0 = NP - 1;
  int gp1 = pb + rowbase + 16 + l15;  if (gp1 >= NP) gp1 = NP - 1;
  const int2 pr0 = ((const int2*)pairs)[gp0];
  const int2 pr1 = ((const int2*)pairs)[gp1];

  f32x4 acc[2][8];
#pragma unroll
  for (int p = 0; p < 2; ++p)
#pragma unroll
    for (int c = 0; c < 8; ++c) acc[p][c] = (f32x4){0.f, 0.f, 0.f, 0.f};

#pragma unroll
  for (int kb = 0; kb < 9; ++kb) {
    short8 a0, a1;
    if (kb < 8) {
      int r0 = (kb < 4) ? pr0.x : pr0.y;
      int r1 = (kb < 4) ? pr1.x : pr1.y;
      int ko = (kb & 3) * 32 + khi;
      a0 = *(const short8*)(xb + (size_t)r0 * 128 + ko);
      a1 = *(const short8*)(xb + (size_t)r1 * 128 + ko);
    } else {
      const float* q0 = pf + (size_t)gp0 * 32 + khi;
      const float* q1 = pf + (size_t)gp1 * 32 + khi;
#pragma unroll
      for (int j = 0; j < 8; ++j) { a0[j] = (short)f2bf(q0[j]); a1[j] = (short)f2bf(q1[j]); }
    }
    const unsigned short* wrow = W1T + (size_t)kb * 32 + khi;
#pragma unroll
    for (int ct = 0; ct < 8; ++ct) {
      short8 bfrag = *(const short8*)(wrow + (size_t)(ct * 16 + l15) * 288);
      acc[0][ct] = __builtin_amdgcn_mfma_f32_16x16x32_bf16(a0, bfrag, acc[0][ct], 0, 0, 0);
      acc[1][ct] = __builtin_amdgcn_mfma_f32_16x16x32_bf16(a1, bfrag, acc[1][ct], 0, 0, 0);
    }
  }

#pragma unroll
  for (int ct = 0; ct < 8; ++ct) {
    float bv = b1[ct * 16 + l15];
    int col = ct * 16 + l15;
#pragma unroll
    for (int p = 0; p < 2; ++p) {
#pragma unroll
      for (int r = 0; r < 4; ++r) {
        int row = rowbase + p * 16 + (lane >> 4) * 4 + r;
        float v = fmaxf(acc[p][ct][r] + bv, 0.f);
        H1[row * 136 + col] = f2bf(v);
      }
    }
  }
  __syncthreads();

  f32x4 acc2[2][4];
#pragma unroll
  for (int p = 0; p < 2; ++p)
#pragma unroll
    for (int c = 0; c < 4; ++c) acc2[p][c] = (f32x4){0.f, 0.f, 0.f, 0.f};

#pragma unroll
  for (int kb = 0; kb < 4; ++kb) {
    int ko = kb * 32 + khi;
    short8 a0 = *(const short8*)&H1[(rowbase + l15) * 136 + ko];
    short8 a1 = *(const short8*)&H1[(rowbase + 16 + l15) * 136 + ko];
    const unsigned short* wrow = W2T + (size_t)ko;
#pragma unroll
    for (int ct = 0; ct < 4; ++ct) {
      short8 bfrag = *(const short8*)(wrow + (size_t)(ct * 16 + l15) * 128);
      acc2[0][ct] = __builtin_amdgcn_mfma_f32_16x16x32_bf16(a0, bfrag, acc2[0][ct], 0, 0, 0);
      acc2[1][ct] = __builtin_amdgcn_mfma_f32_16x16x32_bf16(a1, bfrag, acc2[1][ct], 0, 0, 0);
    }
  }

  float w3v[4], b2v[4];
#pragma unroll
  for (int ct = 0; ct < 4; ++ct) {
    w3v[ct] = W3[ct * 16 + l15];
    b2v[ct] = b2[ct * 16 + l15];
  }
  float b3v = b3[0];
#pragma unroll
  for (int p = 0; p < 2; ++p) {
#pragma unroll
    for (int r = 0; r < 4; ++r) {
      float s = 0.f;
#pragma unroll
      for (int ct = 0; ct < 4; ++ct) {
        float h2 = fmaxf(acc2[p][ct][r] + b2v[ct], 0.f);
        s += h2 * w3v[ct];
      }
      s += __shfl_xor(s, 1);
      s += __shfl_xor(s, 2);
      s += __shfl_xor(s, 4);
      s += __shfl_xor(s, 8);
      int row = pb + rowbase + p * 16 + (lane >> 4) * 4 + r;
      if (l15 == 0 && row < NP) out[row] = s + b3v;
    }
  }
}

// ---------------- launch ----------------

extern "C" void kernel_launch(void* const* d_in, const int* in_sizes, int n_in,
                              void* d_out, int out_size, void* d_ws, size_t ws_size,
                              hipStream_t stream) {
  (void)in_sizes; (void)n_in; (void)out_size; (void)ws_size;
  const float* atom  = (const float*)d_in[0];
  const int*   eidx  = (const int*)d_in[1];
  const int*   pairs = (const int*)d_in[2];
  const float* pfeat = (const float*)d_in[3];
  const float* embW  = (const float*)d_in[4];
  const float* embB  = (const float*)d_in[5];
  const float* convW = (const float*)d_in[6];
  const float* convB = (const float*)d_in[7];
  const float* bng   = (const float*)d_in[8];
  const float* bnb   = (const float*)d_in[9];
  const float* bnm   = (const float*)d_in[10];
  const float* bnv   = (const float*)d_in[11];
  const float* W1    = (const float*)d_in[12];
  const float* b1    = (const float*)d_in[13];
  const float* W2    = (const float*)d_in[14];
  const float* b2    = (const float*)d_in[15];
  const float* W3    = (const float*)d_in[16];
  const float* b3    = (const float*)d_in[17];
  float* out = (float*)d_out;

  uintptr_t base = (uintptr_t)d_ws;
  auto alloc = [&](size_t bytes) -> uintptr_t {
    uintptr_t p = base;
    base += (bytes + 255) & ~(size_t)255;
    return p;
  };
  int*   counts  = (int*)alloc((size_t)NN * 4);
  int*   row_ptr = (int*)alloc((size_t)(NN + 1) * 4);
  int*   cursor  = (int*)alloc((size_t)NN * 4);
  int*   csr_col = (int*)alloc((size_t)NE * 4);
  float* dis     = (float*)alloc((size_t)NN * 4);
  int*   bsum    = (int*)alloc(64 * 4);
  int*   bbase   = (int*)alloc(64 * 4);
  float* xs      = (float*)alloc((size_t)NN * 128 * 4);
  float* y       = (float*)alloc((size_t)NN * 128 * 4);
  unsigned short* embT_hi  = (unsigned short*)alloc(8192 * 2);
  unsigned short* embT_lo  = (unsigned short*)alloc(8192 * 2);
  unsigned short* convT_hi = (unsigned short*)alloc(49152 * 2);
  unsigned short* convT_lo = (unsigned short*)alloc(49152 * 2);
  unsigned short* W1T      = (unsigned short*)alloc(36864 * 2);
  unsigned short* W2T      = (unsigned short*)alloc(8192 * 2);

  unsigned short* x_bf = (unsigned short*)xs;  // overlay: xs dead after last agg

  const int* erow = eidx;
  const int* ecol = eidx + NE;

  hipMemsetAsync(counts, 0, (size_t)NN * 4, stream);
  count_kernel<<<(NE + 255) / 256, 256, 0, stream>>>(erow, counts);
  dis_kernel<<<(NN + 255) / 256, 256, 0, stream>>>(counts, dis);
  scan_partial<<<NB_SCAN, 256, 0, stream>>>(counts, bsum);
  scan_mid<<<1, 64, 0, stream>>>(bsum, bbase);
  scan_final<<<NB_SCAN, 256, 0, stream>>>(counts, bbase, row_ptr, cursor);
  fill_kernel<<<(NE + 255) / 256, 256, 0, stream>>>(erow, ecol, cursor, csr_col);
  prep_w<<<(102400 + 255) / 256, 256, 0, stream>>>(embW, convW, W1, W2,
                                                   embT_hi, embT_lo, convT_hi, convT_lo,
                                                   W1T, W2T);

  // xs0 = dis * (atom @ embW + embB)
  mfma_gemm<64, 0><<<(NN + 63) / 64, 256, 0, stream>>>(
      atom, embT_hi, embT_lo, embB, dis,
      nullptr, nullptr, nullptr, nullptr, xs, nullptr, NN);

  for (int l = 0; l < 3; ++l) {
    agg2_kernel<<<NN, 128, 0, stream>>>(xs, row_ptr, csr_col, dis, y);
    if (l < 2) {
      mfma_gemm<128, 1><<<(NN + 63) / 64, 256, 0, stream>>>(
          y, convT_hi + (size_t)l * 16384, convT_lo + (size_t)l * 16384,
          convB + (size_t)l * 128, dis,
          bng + (size_t)l * 128, bnb + (size_t)l * 128,
          bnm + (size_t)l * 128, bnv + (size_t)l * 128, xs, nullptr, NN);
    } else {
      mfma_gemm<128, 2><<<(NN + 63) / 64, 256, 0, stream>>>(
          y, convT_hi + (size_t)l * 16384, convT_lo + (size_t)l * 16384,
          convB + (size_t)l * 128, nullptr,
          bng + (size_t)l * 128, bnb + (size_t)l * 128,
          bnm + (size_t)l * 128, bnv + (size_t)l * 128, nullptr, x_bf, NN);
    }
  }

  mlp2_kernel<<<(NP + 127) / 128, 256, 0, stream>>>(x_bf, pairs, pfeat,
                                                    W1T, b1, W2T, b2, W3, b3, out);
}

// Round 4
// 364.891 us; speedup vs baseline: 2.8173x; 1.3737x over previous
//
#include <hip/hip_runtime.h>
#include <hip/hip_bf16.h>
#include <stdint.h>

#define NN 50000
#define NE 600000
#define NP 200000
#define SCAN_CHUNK 1024
#define NB_SCAN ((NN + SCAN_CHUNK - 1) / SCAN_CHUNK)   // 49

typedef __attribute__((ext_vector_type(8))) short short8;
typedef __attribute__((ext_vector_type(4))) float f32x4;

static __device__ __forceinline__ unsigned short f2bf(float f) {
  union { float f; unsigned u; } a; a.f = f;
  unsigned r = a.u + 0x7fff + ((a.u >> 16) & 1);
  return (unsigned short)(r >> 16);
}
static __device__ __forceinline__ float bf2f(unsigned short h) {
  union { unsigned u; float f; } a; a.u = ((unsigned)h) << 16;
  return a.f;
}
static __device__ __forceinline__ float lo16f(unsigned w) {
  union { unsigned u; float f; } a; a.u = w << 16; return a.f;
}
static __device__ __forceinline__ float hi16f(unsigned w) {
  union { unsigned u; float f; } a; a.u = w & 0xffff0000u; return a.f;
}

// ---------------- graph build ----------------

__global__ void count_kernel(const int* __restrict__ rows, int* __restrict__ counts) {
  int e = blockIdx.x * 256 + threadIdx.x;
  if (e < NE) atomicAdd(&counts[rows[e]], 1);
}

__global__ void dis_kernel(const int* __restrict__ counts, float* __restrict__ dis) {
  int i = blockIdx.x * 256 + threadIdx.x;
  if (i < NN) dis[i] = rsqrtf((float)counts[i] + 1.0f);
}

__global__ __launch_bounds__(256) void scan_partial(const int* __restrict__ counts,
                                                    int* __restrict__ bsum) {
  const int b = blockIdx.x, t = threadIdx.x;
  const int base = b * SCAN_CHUNK;
  int s = 0;
  for (int j = t; j < SCAN_CHUNK; j += 256) {
    int i = base + j;
    if (i < NN) s += counts[i];
  }
  __shared__ int red[4];
#pragma unroll
  for (int off = 32; off; off >>= 1) s += __shfl_down(s, off);
  if ((t & 63) == 0) red[t >> 6] = s;
  __syncthreads();
  if (t == 0) bsum[b] = red[0] + red[1] + red[2] + red[3];
}

__global__ void scan_mid(const int* __restrict__ bsum, int* __restrict__ bbase) {
  int t = threadIdx.x;  // 64 threads, one wave
  int v = (t < NB_SCAN) ? bsum[t] : 0;
  int orig = v;
#pragma unroll
  for (int off = 1; off < 64; off <<= 1) {
    int u = __shfl_up(v, off);
    if (t >= off) v += u;
  }
  if (t < NB_SCAN) bbase[t] = v - orig;
}

__global__ __launch_bounds__(256) void scan_final(const int* __restrict__ counts,
                                                  const int* __restrict__ bbase,
                                                  int* __restrict__ row_ptr,
                                                  int* __restrict__ cursor) {
  const int b = blockIdx.x, t = threadIdx.x;
  const int i0 = b * SCAN_CHUNK + t * 4;
  int c[4]; int s = 0;
#pragma unroll
  for (int r = 0; r < 4; ++r) { int i = i0 + r; c[r] = (i < NN) ? counts[i] : 0; s += c[r]; }
  __shared__ int sc[256];
  sc[t] = s;
  __syncthreads();
  for (int off = 1; off < 256; off <<= 1) {
    int add = (t >= off) ? sc[t - off] : 0;
    __syncthreads();
    sc[t] += add;
    __syncthreads();
  }
  int run = bbase[b] + sc[t] - s;
#pragma unroll
  for (int r = 0; r < 4; ++r) {
    int i = i0 + r;
    if (i < NN) { row_ptr[i] = run; cursor[i] = run; run += c[r]; }
  }
  if (b == 0 && t == 0) row_ptr[NN] = NE;
}

__global__ void fill_kernel(const int* __restrict__ rows, const int* __restrict__ cols,
                            int* __restrict__ cursor, int* __restrict__ csr_col) {
  int e = blockIdx.x * 256 + threadIdx.x;
  if (e < NE) {
    int r = rows[e];
    int pos = atomicAdd(&cursor[r], 1);
    csr_col[pos] = cols[e];
  }
}

// ---------------- weight prep ----------------

__global__ void prep_w(const float* __restrict__ embW, const float* __restrict__ convW,
                       const float* __restrict__ W1, const float* __restrict__ W2,
                       unsigned short* __restrict__ embT_hi, unsigned short* __restrict__ embT_lo,
                       unsigned short* __restrict__ convT_hi, unsigned short* __restrict__ convT_lo,
                       unsigned short* __restrict__ W1T, unsigned short* __restrict__ W2T) {
  int idx = blockIdx.x * 256 + threadIdx.x;
  if (idx < 8192) {
    int n = idx >> 6, k = idx & 63;
    float v = embW[(size_t)k * 128 + n];
    unsigned short h = f2bf(v);
    embT_hi[idx] = h;
    embT_lo[idx] = f2bf(v - bf2f(h));
  } else if (idx < 8192 + 49152) {
    int i2 = idx - 8192;
    int l = i2 >> 14, n = (i2 >> 7) & 127, k = i2 & 127;
    float v = convW[(size_t)l * 16384 + (size_t)k * 128 + n];
    unsigned short h = f2bf(v);
    convT_hi[i2] = h;
    convT_lo[i2] = f2bf(v - bf2f(h));
  } else if (idx < 8192 + 49152 + 36864) {
    int i3 = idx - 57344;
    int n = i3 / 288, k = i3 % 288;
    W1T[i3] = f2bf(W1[(size_t)k * 128 + n]);
  } else if (idx < 8192 + 49152 + 36864 + 8192) {
    int i4 = idx - 94208;
    int n = i4 >> 7, k = i4 & 127;
    W2T[i4] = f2bf(W2[(size_t)k * 64 + n]);
  }
}

// ---------------- aggregation: y[i] = dis[i]*(xs[i] + sum_{c in N(i)} xs[c]) ----------------
// xs in bf16 (u32-packed pairs), accum fp32, y out fp32. One wave per node.

__global__ __launch_bounds__(256) void agg3_kernel(const unsigned short* __restrict__ xsb,
    const int* __restrict__ row_ptr, const int* __restrict__ csr_col,
    const float* __restrict__ dis, float* __restrict__ y) {
  const int t = threadIdx.x;
  const int n = blockIdx.x * 4 + (t >> 6);
  if (n >= NN) return;
  const int c = t & 63;
  const unsigned* xsw = (const unsigned*)xsb;

  unsigned wself = xsw[(size_t)n * 64 + c];
  float a0 = lo16f(wself), a1 = hi16f(wself);

  const int s = row_ptr[n], e = row_ptr[n + 1];
  int j = s;
  for (; j + 4 <= e; j += 4) {
    int c0 = csr_col[j], c1 = csr_col[j + 1], c2 = csr_col[j + 2], c3 = csr_col[j + 3];
    unsigned w0 = xsw[(size_t)c0 * 64 + c];
    unsigned w1 = xsw[(size_t)c1 * 64 + c];
    unsigned w2 = xsw[(size_t)c2 * 64 + c];
    unsigned w3 = xsw[(size_t)c3 * 64 + c];
    a0 += lo16f(w0) + lo16f(w1) + lo16f(w2) + lo16f(w3);
    a1 += hi16f(w0) + hi16f(w1) + hi16f(w2) + hi16f(w3);
  }
  for (; j < e; ++j) {
    unsigned w0 = xsw[(size_t)csr_col[j] * 64 + c];
    a0 += lo16f(w0);
    a1 += hi16f(w0);
  }
  float dv = dis[n];
  float2 o = make_float2(dv * a0, dv * a1);
  *(float2*)(y + (size_t)n * 128 + c * 2) = o;
}

// ---------------- split-bf16 MFMA GEMM: out_bf16 = epilogue(A[MxK] @ B[Kx128]) ----------------
// 128 rows/block, 4 waves, 2 row-subtiles per wave (B reuse x2).
// MODE 0 (embed): v = dis[row]*(acc + bias)
// MODE 1 (conv l<2): v = dis[row]*relu(BN(acc + bias))
// MODE 2 (conv l=2): v = relu(BN(acc + bias))

template<int K, int MODE>
__global__ __launch_bounds__(256) void mfma_gemm(
    const float* __restrict__ A,
    const unsigned short* __restrict__ BThi, const unsigned short* __restrict__ BTlo,
    const float* __restrict__ bias, const float* __restrict__ dis,
    const float* __restrict__ g, const float* __restrict__ be,
    const float* __restrict__ mn, const float* __restrict__ vr,
    unsigned short* __restrict__ outb, int M) {
  const int tid  = threadIdx.x;
  const int lane = tid & 63;
  const int w    = tid >> 6;
  const int l15  = lane & 15;
  const int khi  = (lane >> 4) * 8;
  const int rowb = blockIdx.x * 128 + w * 32;

  int ar[2];
#pragma unroll
  for (int rt = 0; rt < 2; ++rt) {
    int r = rowb + rt * 16 + l15;
    ar[rt] = (r < M) ? r : M - 1;
  }

  f32x4 acc[2][8];
#pragma unroll
  for (int rt = 0; rt < 2; ++rt)
#pragma unroll
    for (int ct = 0; ct < 8; ++ct) acc[rt][ct] = (f32x4){0.f, 0.f, 0.f, 0.f};

#pragma unroll
  for (int kb = 0; kb < K; kb += 32) {
    short8 ahi[2], alo[2];
#pragma unroll
    for (int rt = 0; rt < 2; ++rt) {
      const float* asrc = A + (size_t)ar[rt] * K + kb + khi;
      float4 va0 = *(const float4*)(asrc);
      float4 va1 = *(const float4*)(asrc + 4);
      float av[8] = {va0.x, va0.y, va0.z, va0.w, va1.x, va1.y, va1.z, va1.w};
#pragma unroll
      for (int j = 0; j < 8; ++j) {
        unsigned short h = f2bf(av[j]);
        ahi[rt][j] = (short)h;
        alo[rt][j] = (short)f2bf(av[j] - bf2f(h));
      }
    }
#pragma unroll
    for (int ct = 0; ct < 8; ++ct) {
      size_t woff = (size_t)(ct * 16 + l15) * K + kb + khi;
      short8 bhi = *(const short8*)(BThi + woff);
      short8 blo = *(const short8*)(BTlo + woff);
#pragma unroll
      for (int rt = 0; rt < 2; ++rt) {
        acc[rt][ct] = __builtin_amdgcn_mfma_f32_16x16x32_bf16(ahi[rt], bhi, acc[rt][ct], 0, 0, 0);
        acc[rt][ct] = __builtin_amdgcn_mfma_f32_16x16x32_bf16(alo[rt], bhi, acc[rt][ct], 0, 0, 0);
        acc[rt][ct] = __builtin_amdgcn_mfma_f32_16x16x32_bf16(ahi[rt], blo, acc[rt][ct], 0, 0, 0);
      }
    }
  }

#pragma unroll
  for (int rt = 0; rt < 2; ++rt) {
    const int orow0 = rowb + rt * 16 + (lane >> 4) * 4;
    float dv[4];
    if constexpr (MODE != 2) {
#pragma unroll
      for (int r = 0; r < 4; ++r) dv[r] = (orow0 + r < M) ? dis[orow0 + r] : 0.f;
    }
#pragma unroll
    for (int ct = 0; ct < 8; ++ct) {
      int col = ct * 16 + l15;
      float bb = bias[col];
      float scale = 1.f, shift = 0.f;
      if constexpr (MODE >= 1) {
        float inv = rsqrtf(vr[col] + 1e-5f);
        scale = g[col] * inv;
        shift = be[col] - mn[col] * scale;
      }
#pragma unroll
      for (int r = 0; r < 4; ++r) {
        int orow = orow0 + r;
        if (orow < M) {
          float v = acc[rt][ct][r] + bb;
          if constexpr (MODE >= 1) v = fmaxf(v * scale + shift, 0.f);
          if constexpr (MODE != 2) v *= dv[r];
          outb[(size_t)orow * 128 + col] = f2bf(v);
        }
      }
    }
  }
}

// ---------------- MFMA pair MLP (preloaded A-fragments) ----------------

__global__ __launch_bounds__(256, 3) void mlp2_kernel(
    const unsigned short* __restrict__ xb, const int* __restrict__ pairs,
    const float* __restrict__ pf,
    const unsigned short* __restrict__ W1T, const float* __restrict__ b1,
    const unsigned short* __restrict__ W2T, const float* __restrict__ b2,
    const float* __restrict__ W3, const float* __restrict__ b3,
    float* __restrict__ out) {
  __shared__ unsigned short H1[128 * 136];

  const int tid  = threadIdx.x;
  const int lane = tid & 63;
  const int w    = tid >> 6;
  const int pb   = blockIdx.x * 128;
  const int rowbase = w * 32;
  const int l15  = lane & 15;
  const int khi  = (lane >> 4) * 8;

  int gp0 = pb + rowbase + l15;       if (gp0 >= NP) gp0 = NP - 1;
  int gp1 = pb + rowbase + 16 + l15;  if (gp1 >= NP) gp1 = NP - 1;
  const int2 pr0 = ((const int2*)pairs)[gp0];
  const int2 pr1 = ((const int2*)pairs)[gp1];

  // ---- preload all phase-1 A fragments: maximize loads in flight ----
  short8 af[18];  // [p*9 + kb]
#pragma unroll
  for (int kb = 0; kb < 4; ++kb) {
    af[kb]     = *(const short8*)(xb + (size_t)pr0.x * 128 + kb * 32 + khi);
    af[4 + kb] = *(const short8*)(xb + (size_t)pr0.y * 128 + kb * 32 + khi);
    af[9 + kb]     = *(const short8*)(xb + (size_t)pr1.x * 128 + kb * 32 + khi);
    af[9 + 4 + kb] = *(const short8*)(xb + (size_t)pr1.y * 128 + kb * 32 + khi);
  }
  {
    const float* q0 = pf + (size_t)gp0 * 32 + khi;
    const float* q1 = pf + (size_t)gp1 * 32 + khi;
    float4 u0 = *(const float4*)(q0), u1 = *(const float4*)(q0 + 4);
    float4 v0 = *(const float4*)(q1), v1 = *(const float4*)(q1 + 4);
    float fu[8] = {u0.x, u0.y, u0.z, u0.w, u1.x, u1.y, u1.z, u1.w};
    float fv[8] = {v0.x, v0.y, v0.z, v0.w, v1.x, v1.y, v1.z, v1.w};
#pragma unroll
    for (int j = 0; j < 8; ++j) {
      af[8][j]  = (short)f2bf(fu[j]);
      af[17][j] = (short)f2bf(fv[j]);
    }
  }

  f32x4 acc[2][8];
#pragma unroll
  for (int p = 0; p < 2; ++p)
#pragma unroll
    for (int c = 0; c < 8; ++c) acc[p][c] = (f32x4){0.f, 0.f, 0.f, 0.f};

  // ---- phase 1 MFMAs: H1 = relu(Z @ W1 + b1), K=288 ----
#pragma unroll
  for (int kb = 0; kb < 9; ++kb) {
    const unsigned short* wrow = W1T + (size_t)kb * 32 + khi;
#pragma unroll
    for (int ct = 0; ct < 8; ++ct) {
      short8 bfrag = *(const short8*)(wrow + (size_t)(ct * 16 + l15) * 288);
      acc[0][ct] = __builtin_amdgcn_mfma_f32_16x16x32_bf16(af[kb], bfrag, acc[0][ct], 0, 0, 0);
      acc[1][ct] = __builtin_amdgcn_mfma_f32_16x16x32_bf16(af[9 + kb], bfrag, acc[1][ct], 0, 0, 0);
    }
  }

#pragma unroll
  for (int ct = 0; ct < 8; ++ct) {
    float bv = b1[ct * 16 + l15];
    int col = ct * 16 + l15;
#pragma unroll
    for (int p = 0; p < 2; ++p) {
#pragma unroll
      for (int r = 0; r < 4; ++r) {
        int row = rowbase + p * 16 + (lane >> 4) * 4 + r;
        float v = fmaxf(acc[p][ct][r] + bv, 0.f);
        H1[row * 136 + col] = f2bf(v);
      }
    }
  }
  __syncthreads();

  // ---- phase 2: H2 = relu(H1 @ W2 + b2), K=128 ----
  f32x4 acc2[2][4];
#pragma unroll
  for (int p = 0; p < 2; ++p)
#pragma unroll
    for (int c = 0; c < 4; ++c) acc2[p][c] = (f32x4){0.f, 0.f, 0.f, 0.f};

#pragma unroll
  for (int kb = 0; kb < 4; ++kb) {
    int ko = kb * 32 + khi;
    short8 a0 = *(const short8*)&H1[(rowbase + l15) * 136 + ko];
    short8 a1 = *(const short8*)&H1[(rowbase + 16 + l15) * 136 + ko];
    const unsigned short* wrow = W2T + (size_t)ko;
#pragma unroll
    for (int ct = 0; ct < 4; ++ct) {
      short8 bfrag = *(const short8*)(wrow + (size_t)(ct * 16 + l15) * 128);
      acc2[0][ct] = __builtin_amdgcn_mfma_f32_16x16x32_bf16(a0, bfrag, acc2[0][ct], 0, 0, 0);
      acc2[1][ct] = __builtin_amdgcn_mfma_f32_16x16x32_bf16(a1, bfrag, acc2[1][ct], 0, 0, 0);
    }
  }

  // ---- phase 3: out = relu(H2 + b2) . W3 + b3 ----
  float w3v[4], b2v[4];
#pragma unroll
  for (int ct = 0; ct < 4; ++ct) {
    w3v[ct] = W3[ct * 16 + l15];
    b2v[ct] = b2[ct * 16 + l15];
  }
  float b3v = b3[0];
#pragma unroll
  for (int p = 0; p < 2; ++p) {
#pragma unroll
    for (int r = 0; r < 4; ++r) {
      float s = 0.f;
#pragma unroll
      for (int ct = 0; ct < 4; ++ct) {
        float h2 = fmaxf(acc2[p][ct][r] + b2v[ct], 0.f);
        s += h2 * w3v[ct];
      }
      s += __shfl_xor(s, 1);
      s += __shfl_xor(s, 2);
      s += __shfl_xor(s, 4);
      s += __shfl_xor(s, 8);
      int row = pb + rowbase + p * 16 + (lane >> 4) * 4 + r;
      if (l15 == 0 && row < NP) out[row] = s + b3v;
    }
  }
}

// ---------------- launch ----------------

extern "C" void kernel_launch(void* const* d_in, const int* in_sizes, int n_in,
                              void* d_out, int out_size, void* d_ws, size_t ws_size,
                              hipStream_t stream) {
  (void)in_sizes; (void)n_in; (void)out_size; (void)ws_size;
  const float* atom  = (const float*)d_in[0];
  const int*   eidx  = (const int*)d_in[1];
  const int*   pairs = (const int*)d_in[2];
  const float* pfeat = (const float*)d_in[3];
  const float* embW  = (const float*)d_in[4];
  const float* embB  = (const float*)d_in[5];
  const float* convW = (const float*)d_in[6];
  const float* convB = (const float*)d_in[7];
  const float* bng   = (const float*)d_in[8];
  const float* bnb   = (const float*)d_in[9];
  const float* bnm   = (const float*)d_in[10];
  const float* bnv   = (const float*)d_in[11];
  const float* W1    = (const float*)d_in[12];
  const float* b1    = (const float*)d_in[13];
  const float* W2    = (const float*)d_in[14];
  const float* b2    = (const float*)d_in[15];
  const float* W3    = (const float*)d_in[16];
  const float* b3    = (const float*)d_in[17];
  float* out = (float*)d_out;

  uintptr_t base = (uintptr_t)d_ws;
  auto alloc = [&](size_t bytes) -> uintptr_t {
    uintptr_t p = base;
    base += (bytes + 255) & ~(size_t)255;
    return p;
  };
  int*   counts  = (int*)alloc((size_t)NN * 4);
  int*   row_ptr = (int*)alloc((size_t)(NN + 1) * 4);
  int*   cursor  = (int*)alloc((size_t)NN * 4);
  int*   csr_col = (int*)alloc((size_t)NE * 4);
  float* dis     = (float*)alloc((size_t)NN * 4);
  int*   bsum    = (int*)alloc(64 * 4);
  int*   bbase   = (int*)alloc(64 * 4);
  unsigned short* xs_bf = (unsigned short*)alloc((size_t)NN * 128 * 2);
  float* y       = (float*)alloc((size_t)NN * 128 * 4);
  unsigned short* embT_hi  = (unsigned short*)alloc(8192 * 2);
  unsigned short* embT_lo  = (unsigned short*)alloc(8192 * 2);
  unsigned short* convT_hi = (unsigned short*)alloc(49152 * 2);
  unsigned short* convT_lo = (unsigned short*)alloc(49152 * 2);
  unsigned short* W1T      = (unsigned short*)alloc(36864 * 2);
  unsigned short* W2T      = (unsigned short*)alloc(8192 * 2);

  const int* erow = eidx;
  const int* ecol = eidx + NE;

  hipMemsetAsync(counts, 0, (size_t)NN * 4, stream);
  count_kernel<<<(NE + 255) / 256, 256, 0, stream>>>(erow, counts);
  dis_kernel<<<(NN + 255) / 256, 256, 0, stream>>>(counts, dis);
  scan_partial<<<NB_SCAN, 256, 0, stream>>>(counts, bsum);
  scan_mid<<<1, 64, 0, stream>>>(bsum, bbase);
  scan_final<<<NB_SCAN, 256, 0, stream>>>(counts, bbase, row_ptr, cursor);
  fill_kernel<<<(NE + 255) / 256, 256, 0, stream>>>(erow, ecol, cursor, csr_col);
  prep_w<<<(102400 + 255) / 256, 256, 0, stream>>>(embW, convW, W1, W2,
                                                   embT_hi, embT_lo, convT_hi, convT_lo,
                                                   W1T, W2T);

  // xs0 = bf16( dis * (atom @ embW + embB) )
  mfma_gemm<64, 0><<<(NN + 127) / 128, 256, 0, stream>>>(
      atom, embT_hi, embT_lo, embB, dis,
      nullptr, nullptr, nullptr, nullptr, xs_bf, NN);

  for (int l = 0; l < 3; ++l) {
    agg3_kernel<<<(NN + 3) / 4, 256, 0, stream>>>(xs_bf, row_ptr, csr_col, dis, y);
    if (l < 2) {
      mfma_gemm<128, 1><<<(NN + 127) / 128, 256, 0, stream>>>(
          y, convT_hi + (size_t)l * 16384, convT_lo + (size_t)l * 16384,
          convB + (size_t)l * 128, dis,
          bng + (size_t)l * 128, bnb + (size_t)l * 128,
          bnm + (size_t)l * 128, bnv + (size_t)l * 128, xs_bf, NN);
    } else {
      mfma_gemm<128, 2><<<(NN + 127) / 128, 256, 0, stream>>>(
          y, convT_hi + (size_t)l * 16384, convT_lo + (size_t)l * 16384,
          convB + (size_t)l * 128, nullptr,
          bng + (size_t)l * 128, bnb + (size_t)l * 128,
          bnm + (size_t)l * 128, bnv + (size_t)l * 128, xs_bf, NN);
    }
  }

  mlp2_kernel<<<(NP + 127) / 128, 256, 0, stream>>>(xs_bf, pairs, pfeat,
                                                    W1T, b1, W2T, b2, W3, b3, out);
}